// Round 2
// baseline (174.772 us; speedup 1.0000x reference)
//
#include <hip/hip_runtime.h>
#include <stdint.h>

// SelfAttention1D: B=8, C=256, L=2048, D=32, fp32 in/out, bf16 MFMA compute.
//
// ws layout (bytes):
//   Wh  @ 0x000000 : bf16 [320][256]   rows 0-31 Wq, 32-63 Wk, 64-319 Wv (160 KB)
//   Qh  @ 0x040000 : bf16 [B][L][32]   Q pre-scaled by (1/sqrt(D))*log2(e) (1 MB)
//   Kth @ 0x140000 : bf16 [B][L][32]   K^T, d-contiguous (1 MB)
//   Vh  @ 0x240000 : bf16 [B][256][L]  V, j-contiguous (8 MB)
// total 10.25 MB

#define BB 8
#define CC 256
#define LL 2048
#define DD 32

typedef unsigned short u16;
typedef __attribute__((ext_vector_type(8))) short short8;
typedef __attribute__((ext_vector_type(4))) float f32x4;

#define SCALE_LOG2E 0.2550348612f

static __device__ __forceinline__ uint32_t pack2bf16(float hi, float lo) {
    return (__float_as_uint(hi) & 0xFFFF0000u) | (__float_as_uint(lo) >> 16);
}

static __device__ __forceinline__ float fexp2(float v) {
#if __has_builtin(__builtin_amdgcn_exp2f)
    return __builtin_amdgcn_exp2f(v);
#else
    return exp2f(v);
#endif
}

static __device__ __forceinline__ float frcp(float v) {
#if __has_builtin(__builtin_amdgcn_rcpf)
    return __builtin_amdgcn_rcpf(v);
#else
    return 1.0f / v;
#endif
}

// ---------------- kernel 1: W -> bf16 ----------------
__global__ __launch_bounds__(256) void prep_w_kernel(
    const float* __restrict__ Wq, const float* __restrict__ Wk,
    const float* __restrict__ Wv, u16* __restrict__ Wh)
{
    int idx = blockIdx.x * 256 + threadIdx.x;     // 320 rows * 64 float4
    int r = idx >> 6;
    int c4 = (idx & 63) << 2;
    const float* src;
    if (r < 32)       src = Wq + (size_t)r * CC + c4;
    else if (r < 64)  src = Wk + (size_t)(r - 32) * CC + c4;
    else              src = Wv + (size_t)(r - 64) * CC + c4;
    float4 v = *(const float4*)src;
    uint2 o;
    o.x = pack2bf16(v.y, v.x);
    o.y = pack2bf16(v.w, v.z);
    *(uint2*)(Wh + (size_t)r * CC + c4) = o;
}

// ---------------- kernel 2: QKV projection ----------------
// grid 512 = 8 b x 64 l-tiles(32), 512 thr (8 waves), 2 blocks/CU.
__global__ __launch_bounds__(512, 2) void proj_kernel(
    const float* __restrict__ x, const u16* __restrict__ Wh,
    const float* __restrict__ bq, const float* __restrict__ bk,
    const float* __restrict__ bv,
    u16* __restrict__ Qh, u16* __restrict__ Kth, u16* __restrict__ Vh)
{
    __shared__ u16 xls[32 * 264];        // 16.9 KB
    const int blk = blockIdx.x;
    const int b = blk & 7;
    const int l0 = (blk >> 3) << 5;
    const int tid = threadIdx.x;
    const int w = tid >> 6;
    const int lane = tid & 63;
    const int ln = lane & 15;
    const int q = lane >> 4;

#pragma unroll
    for (int cc = 0; cc < 4; ++cc) {
        const int c = cc * 64 + (tid >> 3);
        const int l4 = (tid & 7) * 4;
        const float4 v = *(const float4*)(x + ((size_t)(b * CC + c)) * LL + l0 + l4);
        xls[(l4 + 0) * 264 + c] = (u16)(__float_as_uint(v.x) >> 16);
        xls[(l4 + 1) * 264 + c] = (u16)(__float_as_uint(v.y) >> 16);
        xls[(l4 + 2) * 264 + c] = (u16)(__float_as_uint(v.z) >> 16);
        xls[(l4 + 3) * 264 + c] = (u16)(__float_as_uint(v.w) >> 16);
    }
    __syncthreads();

    const int wl = w & 1;
    const int wm = w >> 1;               // 0..3 -> 80 rows each
    const int mbase = wm * 80;
    const int l = l0 + wl * 16 + ln;

    f32x4 acc[5];
#pragma unroll
    for (int i = 0; i < 5; ++i) acc[i] = (f32x4){0.f, 0.f, 0.f, 0.f};

#pragma unroll
    for (int c0 = 0; c0 < CC; c0 += 32) {
        const short8 bf = *(const short8*)(&xls[(wl * 16 + ln) * 264 + c0 + q * 8]);
#pragma unroll
        for (int mt = 0; mt < 5; ++mt) {
            const short8 af = *(const short8*)(Wh + (size_t)(mbase + mt * 16 + ln) * CC + c0 + q * 8);
            acc[mt] = __builtin_amdgcn_mfma_f32_16x16x32_bf16(af, bf, acc[mt], 0, 0, 0);
        }
    }

#pragma unroll
    for (int mt = 0; mt < 5; ++mt) {
        const int rg = mbase + mt * 16 + q * 4;   // global output row
        if (rg < 32) {                   // Q rows, pre-scaled
            float v0 = (acc[mt][0] + bq[rg + 0]) * SCALE_LOG2E;
            float v1 = (acc[mt][1] + bq[rg + 1]) * SCALE_LOG2E;
            float v2 = (acc[mt][2] + bq[rg + 2]) * SCALE_LOG2E;
            float v3 = (acc[mt][3] + bq[rg + 3]) * SCALE_LOG2E;
            uint2 o; o.x = pack2bf16(v1, v0); o.y = pack2bf16(v3, v2);
            *(uint2*)(Qh + ((size_t)(b * LL) + l) * DD + rg) = o;
        } else if (rg < 64) {            // K rows
            const int rk = rg - 32;
            float v0 = acc[mt][0] + bk[rk + 0];
            float v1 = acc[mt][1] + bk[rk + 1];
            float v2 = acc[mt][2] + bk[rk + 2];
            float v3 = acc[mt][3] + bk[rk + 3];
            uint2 o; o.x = pack2bf16(v1, v0); o.y = pack2bf16(v3, v2);
            *(uint2*)(Kth + ((size_t)(b * LL) + l) * DD + rk) = o;
        } else {                         // V rows -> Vh[b][c][l]
            const int cv = rg - 64;
#pragma unroll
            for (int rr = 0; rr < 4; ++rr) {
                const float v = acc[mt][rr] + bv[cv + rr];
                Vh[((size_t)(b * CC) + cv + rr) * LL + l] = (u16)(__float_as_uint(v) >> 16);
            }
        }
    }
}

// ---------------- kernel 3: fused attention (barrier-free main loop, i-tile 32) ----------------
// grid 512 = (b = blk&7 -> XCD L2 affinity) x (i-tile 32). 512 thr (8 waves):
// wc = w>>2 (c-half 128), wj = w&3 (j-slices jb = n*128 + wj*32, n=0..15).
// Each wave independently: S^T = K.Q^T (4 MFMA) -> exp2 -> P via wave-PRIVATE
// LDS (no __syncthreads in main loop) -> O^T += V.P^T (16 MFMA). V prefetch
// split in two 4-frag groups to stay <=128 VGPR -> 2 blocks/CU = 4 waves/SIMD
// (vs round-0's 1 block/CU). l accumulated in-register. Epilogue: O reduced
// over wj via 4 barriered LDS passes, coalesced float4 finalize.
__global__ __launch_bounds__(512, 4) void attn_kernel(
    const u16* __restrict__ Qh, const u16* __restrict__ Kth,
    const u16* __restrict__ Vh, const float* __restrict__ x,
    const float* __restrict__ gamma, float* __restrict__ out)
{
    __shared__ __attribute__((aligned(16))) u16 pbuf[8][32][40]; // 20 KB
    __shared__ float obuf[256][36];                              // 36.9 KB
    __shared__ float lbuf[8][32];                                // 1 KB

    const int blk = blockIdx.x;
    const int b = blk & 7;
    const int i0 = (blk >> 3) << 5;      // i-tile of 32
    const int tid = threadIdx.x;
    const int w = tid >> 6;              // 0..7
    const int wc = w >> 2;               // 0..1
    const int wj = w & 3;                // 0..3
    const int lane = tid & 63;
    const int ln = lane & 15;
    const int q = lane >> 4;

    u16* pb = &pbuf[w][0][0];
    const u16* Qb = Qh + ((size_t)(b * LL) + i0) * DD;
    const u16* Kb = Kth + (size_t)(b * LL) * DD;
    const u16* Vb = Vh + ((size_t)(b * CC) + wc * 128) * LL;

    short8 qf[2];
#pragma unroll
    for (int it = 0; it < 2; ++it)
        qf[it] = *(const short8*)(Qb + (size_t)(it * 16 + ln) * DD + q * 8);

    const f32x4 zf = {0.f, 0.f, 0.f, 0.f};
    f32x4 oacc[8][2];                    // [ct][it] = 64 regs (accumulator file)
#pragma unroll
    for (int a = 0; a < 8; ++a)
#pragma unroll
        for (int c = 0; c < 2; ++c) oacc[a][c] = zf;
    float lsum[2] = {0.f, 0.f};

    for (int n = 0; n < 16; ++n) {
        const int jb = n * 128 + wj * 32;

        // first V-group + K loads issue up front (consumed after S -> latency hidden)
        short8 vf0[4];
#pragma unroll
        for (int ct = 0; ct < 4; ++ct)
            vf0[ct] = *(const short8*)(Vb + (size_t)(ct * 16 + ln) * LL + jb + q * 8);
        const short8 kf0 = *(const short8*)(Kb + (size_t)(jb + ln) * DD + q * 8);
        const short8 kf1 = *(const short8*)(Kb + (size_t)(jb + 16 + ln) * DD + q * 8);

        // ---- S phase: S^T = K.Q^T (32 j x 32 i), exp2, P -> private LDS ----
#pragma unroll
        for (int jt = 0; jt < 2; ++jt) {
            const short8 kf = jt ? kf1 : kf0;
#pragma unroll
            for (int it = 0; it < 2; ++it) {
                const f32x4 st = __builtin_amdgcn_mfma_f32_16x16x32_bf16(kf, qf[it], zf, 0, 0, 0);
                const float e0 = fexp2(st[0]), e1 = fexp2(st[1]);
                const float e2 = fexp2(st[2]), e3 = fexp2(st[3]);
                lsum[it] += (e0 + e1) + (e2 + e3);
                uint2 d; d.x = pack2bf16(e1, e0); d.y = pack2bf16(e3, e2);
                *(uint2*)(&pb[(it * 16 + ln) * 40 + jt * 16 + q * 4]) = d;
            }
        }

        // second V-group issues here; latency covered by P readback + first PV half
        short8 vf1[4];
#pragma unroll
        for (int ct = 0; ct < 4; ++ct)
            vf1[ct] = *(const short8*)(Vb + (size_t)((ct + 4) * 16 + ln) * LL + jb + q * 8);

        // ---- read back as B-frags (same wave; compiler emits lgkmcnt wait) ----
        short8 pf[2];
#pragma unroll
        for (int it = 0; it < 2; ++it)
            pf[it] = *(const short8*)(&pb[(it * 16 + ln) * 40 + q * 8]);

        // ---- PV: O^T += V.P^T over exclusive 128-c half ----
#pragma unroll
        for (int ct = 0; ct < 4; ++ct)
#pragma unroll
            for (int it = 0; it < 2; ++it)
                oacc[ct][it] = __builtin_amdgcn_mfma_f32_16x16x32_bf16(vf0[ct], pf[it], oacc[ct][it], 0, 0, 0);
#pragma unroll
        for (int ct = 0; ct < 4; ++ct)
#pragma unroll
            for (int it = 0; it < 2; ++it)
                oacc[4 + ct][it] = __builtin_amdgcn_mfma_f32_16x16x32_bf16(vf1[ct], pf[it], oacc[4 + ct][it], 0, 0, 0);
    }

    // ---- l: reduce over q within wave; publish per-wave partials ----
#pragma unroll
    for (int it = 0; it < 2; ++it) {
        float s = lsum[it];
        s += __shfl_xor(s, 16);
        s += __shfl_xor(s, 32);
        lsum[it] = s;
    }
    if (q == 0) {
        lbuf[w][ln] = lsum[0];
        lbuf[w][16 + ln] = lsum[1];
    }

    // ---- O reduction over wj (4 serialized passes, disjoint c across wc) ----
#pragma unroll
    for (int p = 0; p < 4; ++p) {
        if (wj == p) {
#pragma unroll
            for (int ct = 0; ct < 8; ++ct)
#pragma unroll
                for (int it = 0; it < 2; ++it) {
                    const int i = it * 16 + ln;
#pragma unroll
                    for (int r = 0; r < 4; ++r) {
                        const int c = wc * 128 + ct * 16 + q * 4 + r;
                        if (p == 0) obuf[c][i] = oacc[ct][it][r];
                        else        obuf[c][i] += oacc[ct][it][r];
                    }
                }
        }
        __syncthreads();
    }

    // ---- finalize: out = gamma * O/l + x (coalesced float4) ----
    // lbuf summed over all 8 waves double-counts l (2 wc duplicates) -> 2/s.
    const float g = gamma[0];
    const int i4 = (tid & 7) * 4;
    float4 sv = {0.f, 0.f, 0.f, 0.f};
#pragma unroll
    for (int ww = 0; ww < 8; ++ww) {
        const float4 lv = *(const float4*)&lbuf[ww][i4];
        sv.x += lv.x; sv.y += lv.y; sv.z += lv.z; sv.w += lv.w;
    }
    float4 li;
    li.x = 2.0f * frcp(sv.x); li.y = 2.0f * frcp(sv.y);
    li.z = 2.0f * frcp(sv.z); li.w = 2.0f * frcp(sv.w);

#pragma unroll
    for (int cc = 0; cc < 4; ++cc) {
        const int c = cc * 64 + (tid >> 3);
        const float4 ov = *(const float4*)&obuf[c][i4];
        const size_t idx = ((size_t)(b * CC + c)) * LL + i0 + i4;
        const float4 xv = *(const float4*)(x + idx);
        float4 o;
        o.x = g * (ov.x * li.x) + xv.x;
        o.y = g * (ov.y * li.y) + xv.y;
        o.z = g * (ov.z * li.z) + xv.z;
        o.w = g * (ov.w * li.w) + xv.w;
        *(float4*)(out + idx) = o;
    }
}

// ---------------- launcher ----------------
extern "C" void kernel_launch(void* const* d_in, const int* in_sizes, int n_in,
                              void* d_out, int out_size, void* d_ws, size_t ws_size,
                              hipStream_t stream)
{
    const float* x     = (const float*)d_in[0];
    const float* Wq    = (const float*)d_in[1];
    const float* bq    = (const float*)d_in[2];
    const float* Wk    = (const float*)d_in[3];
    const float* bk    = (const float*)d_in[4];
    const float* Wv    = (const float*)d_in[5];
    const float* bv    = (const float*)d_in[6];
    const float* gamma = (const float*)d_in[7];
    float* out = (float*)d_out;

    uint8_t* ws = (uint8_t*)d_ws;
    u16* Wh  = (u16*)(ws + 0x000000);
    u16* Qh  = (u16*)(ws + 0x040000);
    u16* Kth = (u16*)(ws + 0x140000);
    u16* Vh  = (u16*)(ws + 0x240000);

    prep_w_kernel<<<80, 256, 0, stream>>>(Wq, Wk, Wv, Wh);
    proj_kernel<<<512, 512, 0, stream>>>(x, Wh, bq, bk, bv, Qh, Kth, Vh);
    attn_kernel<<<512, 512, 0, stream>>>(Qh, Kth, Vh, x, gamma, out);
}

// Round 3
// 153.264 us; speedup vs baseline: 1.1403x; 1.1403x over previous
//
#include <hip/hip_runtime.h>
#include <stdint.h>

// SelfAttention1D: B=8, C=256, L=2048, D=32, fp32 in/out, bf16 MFMA compute.
//
// ws layout (bytes):
//   Wh  @ 0x000000 : bf16 [320][256]   rows 0-31 Wq, 32-63 Wk, 64-319 Wv (160 KB)
//   Qh  @ 0x040000 : bf16 [B][L][32]   Q pre-scaled by (1/sqrt(D))*log2(e) (1 MB)
//   Kth @ 0x140000 : bf16 [B][L][32]   K^T, d-contiguous (1 MB)
//   Vh  @ 0x240000 : bf16 [B][256][L]  V, j-contiguous (8 MB)
// total 10.25 MB

#define BB 8
#define CC 256
#define LL 2048
#define DD 32

typedef unsigned short u16;
typedef __attribute__((ext_vector_type(8))) short short8;
typedef __attribute__((ext_vector_type(4))) float f32x4;

#define SCALE_LOG2E 0.2550348612f

static __device__ __forceinline__ uint32_t pack2bf16(float hi, float lo) {
    return (__float_as_uint(hi) & 0xFFFF0000u) | (__float_as_uint(lo) >> 16);
}

static __device__ __forceinline__ float fexp2(float v) {
#if __has_builtin(__builtin_amdgcn_exp2f)
    return __builtin_amdgcn_exp2f(v);
#else
    return exp2f(v);
#endif
}

static __device__ __forceinline__ float frcp(float v) {
#if __has_builtin(__builtin_amdgcn_rcpf)
    return __builtin_amdgcn_rcpf(v);
#else
    return 1.0f / v;
#endif
}

// ---------------- kernel 1: W -> bf16 ----------------
__global__ __launch_bounds__(256) void prep_w_kernel(
    const float* __restrict__ Wq, const float* __restrict__ Wk,
    const float* __restrict__ Wv, u16* __restrict__ Wh)
{
    int idx = blockIdx.x * 256 + threadIdx.x;     // 320 rows * 64 float4
    int r = idx >> 6;
    int c4 = (idx & 63) << 2;
    const float* src;
    if (r < 32)       src = Wq + (size_t)r * CC + c4;
    else if (r < 64)  src = Wk + (size_t)(r - 32) * CC + c4;
    else              src = Wv + (size_t)(r - 64) * CC + c4;
    float4 v = *(const float4*)src;
    uint2 o;
    o.x = pack2bf16(v.y, v.x);
    o.y = pack2bf16(v.w, v.z);
    *(uint2*)(Wh + (size_t)r * CC + c4) = o;
}

// ---------------- kernel 2: QKV projection ----------------
// grid 512 = 8 b x 64 l-tiles(32), 512 thr (8 waves), 2 blocks/CU.
// V output now staged through LDS transpose tile (vls) and stored as
// coalesced dwordx4 (was: 12 scattered scalar u16 stores per thread).
__global__ __launch_bounds__(512, 2) void proj_kernel(
    const float* __restrict__ x, const u16* __restrict__ Wh,
    const float* __restrict__ bq, const float* __restrict__ bk,
    const float* __restrict__ bv,
    u16* __restrict__ Qh, u16* __restrict__ Kth, u16* __restrict__ Vh)
{
    __shared__ u16 xls[32 * 264];        // 16.9 KB
    __shared__ __attribute__((aligned(16))) u16 vls[256 * 40]; // 20.5 KB
    const int blk = blockIdx.x;
    const int b = blk & 7;
    const int l0 = (blk >> 3) << 5;
    const int tid = threadIdx.x;
    const int w = tid >> 6;
    const int lane = tid & 63;
    const int ln = lane & 15;
    const int q = lane >> 4;

#pragma unroll
    for (int cc = 0; cc < 4; ++cc) {
        const int c = cc * 64 + (tid >> 3);
        const int l4 = (tid & 7) * 4;
        const float4 v = *(const float4*)(x + ((size_t)(b * CC + c)) * LL + l0 + l4);
        xls[(l4 + 0) * 264 + c] = (u16)(__float_as_uint(v.x) >> 16);
        xls[(l4 + 1) * 264 + c] = (u16)(__float_as_uint(v.y) >> 16);
        xls[(l4 + 2) * 264 + c] = (u16)(__float_as_uint(v.z) >> 16);
        xls[(l4 + 3) * 264 + c] = (u16)(__float_as_uint(v.w) >> 16);
    }
    __syncthreads();

    const int wl = w & 1;
    const int wm = w >> 1;               // 0..3 -> 80 rows each
    const int mbase = wm * 80;
    const int l = l0 + wl * 16 + ln;
    const int li = wl * 16 + ln;

    f32x4 acc[5];
#pragma unroll
    for (int i = 0; i < 5; ++i) acc[i] = (f32x4){0.f, 0.f, 0.f, 0.f};

#pragma unroll
    for (int c0 = 0; c0 < CC; c0 += 32) {
        const short8 bf = *(const short8*)(&xls[(wl * 16 + ln) * 264 + c0 + q * 8]);
#pragma unroll
        for (int mt = 0; mt < 5; ++mt) {
            const short8 af = *(const short8*)(Wh + (size_t)(mbase + mt * 16 + ln) * CC + c0 + q * 8);
            acc[mt] = __builtin_amdgcn_mfma_f32_16x16x32_bf16(af, bf, acc[mt], 0, 0, 0);
        }
    }

#pragma unroll
    for (int mt = 0; mt < 5; ++mt) {
        const int rg = mbase + mt * 16 + q * 4;   // global output row
        if (rg < 32) {                   // Q rows, pre-scaled
            float v0 = (acc[mt][0] + bq[rg + 0]) * SCALE_LOG2E;
            float v1 = (acc[mt][1] + bq[rg + 1]) * SCALE_LOG2E;
            float v2 = (acc[mt][2] + bq[rg + 2]) * SCALE_LOG2E;
            float v3 = (acc[mt][3] + bq[rg + 3]) * SCALE_LOG2E;
            uint2 o; o.x = pack2bf16(v1, v0); o.y = pack2bf16(v3, v2);
            *(uint2*)(Qh + ((size_t)(b * LL) + l) * DD + rg) = o;
        } else if (rg < 64) {            // K rows
            const int rk = rg - 32;
            float v0 = acc[mt][0] + bk[rk + 0];
            float v1 = acc[mt][1] + bk[rk + 1];
            float v2 = acc[mt][2] + bk[rk + 2];
            float v3 = acc[mt][3] + bk[rk + 3];
            uint2 o; o.x = pack2bf16(v1, v0); o.y = pack2bf16(v3, v2);
            *(uint2*)(Kth + ((size_t)(b * LL) + l) * DD + rk) = o;
        } else {                         // V rows -> LDS transpose tile
            const int cv = rg - 64;
#pragma unroll
            for (int rr = 0; rr < 4; ++rr) {
                const float v = acc[mt][rr] + bv[cv + rr];
                vls[(cv + rr) * 40 + li] = (u16)(__float_as_uint(v) >> 16);
            }
        }
    }

    __syncthreads();
    // cooperative coalesced V store: 256 rows x 64 B
    {
        const int row = tid >> 1;
        const int h = (tid & 1) * 16;    // u16 offset within row
        const u16* src = &vls[row * 40 + h];
        const uint4 v0 = *(const uint4*)(src);
        const uint4 v1 = *(const uint4*)(src + 8);
        uint4* dst = (uint4*)(Vh + ((size_t)(b * CC) + row) * LL + l0 + h);
        dst[0] = v0;
        dst[1] = v1;
    }
}

// ---------------- kernel 3: fused attention (R0 structure + S/PV software pipeline) ----------------
// grid 256 = (b = blk&7 -> XCD L2 affinity) x (i-tile 64). 512 thr (8 waves):
// wc = w>>2 (c-half 128), wj = w&3 (j-slices jb = n*128 + wj*32, n=0..15).
// Barrier-free main loop. NEW vs R0: S phase runs ONE ITERATION AHEAD --
// iter n computes S_{n+1} (K.Q^T -> exp2 -> P into pbuf[(n+1)&1]) between
// reading P_n and running PV_n, so the P LDS round-trip overlaps PV's 32
// MFMAs, K has a full iteration of load slack (prefetched 2 tiles ahead),
// and V loads get the whole S phase as slack. P double-buffered (80 KB).
__global__ __launch_bounds__(512, 1) void attn_kernel(
    const u16* __restrict__ Qh, const u16* __restrict__ Kth,
    const u16* __restrict__ Vh, const float* __restrict__ x,
    const float* __restrict__ gamma, float* __restrict__ out)
{
    __shared__ __attribute__((aligned(16))) u16 pbuf[2][8][64 * 40]; // 80 KB
    __shared__ float obuf[256 * 68];     // 69.6 KB
    __shared__ float lbuf[8 * 64];       // 2 KB

    const int blk = blockIdx.x;
    const int b = blk & 7;
    const int i0 = (blk >> 3) << 6;
    const int tid = threadIdx.x;
    const int w = tid >> 6;              // 0..7
    const int wc = w >> 2;               // 0..1
    const int wj = w & 3;                // 0..3
    const int lane = tid & 63;
    const int ln = lane & 15;
    const int q = lane >> 4;

    const u16* Qb = Qh + ((size_t)(b * LL) + i0) * DD;
    const u16* Kb = Kth + (size_t)(b * LL) * DD;
    const u16* Vb = Vh + ((size_t)(b * CC) + wc * 128) * LL;

    short8 qf[4];
#pragma unroll
    for (int it = 0; it < 4; ++it)
        qf[it] = *(const short8*)(Qb + (size_t)(it * 16 + ln) * DD + q * 8);

    const f32x4 zf = {0.f, 0.f, 0.f, 0.f};
    f32x4 oacc[8][4];                    // [ct][it] = 128 regs
#pragma unroll
    for (int a = 0; a < 8; ++a)
#pragma unroll
        for (int c = 0; c < 4; ++c) oacc[a][c] = zf;
    float lsum[4] = {0.f, 0.f, 0.f, 0.f};

    // S phase: S^T = K.Q^T for one 32-j slice -> exp2 -> P into pbuf[slot]
    auto Sphase = [&](int slot, short8 ka, short8 kb) {
        u16* pw = &pbuf[slot][w][0];
#pragma unroll
        for (int jt = 0; jt < 2; ++jt) {
            const short8 kf = jt ? kb : ka;
#pragma unroll
            for (int it = 0; it < 4; ++it) {
                const f32x4 st = __builtin_amdgcn_mfma_f32_16x16x32_bf16(kf, qf[it], zf, 0, 0, 0);
                const float e0 = fexp2(st[0]), e1 = fexp2(st[1]);
                const float e2 = fexp2(st[2]), e3 = fexp2(st[3]);
                lsum[it] += (e0 + e1) + (e2 + e3);
                uint2 d; d.x = pack2bf16(e1, e0); d.y = pack2bf16(e3, e2);
                *(uint2*)(&pw[(it * 16 + ln) * 40 + jt * 16 + q * 4]) = d;
            }
        }
    };

    // prologue: S_0 -> pbuf[0]; then kA = K frags for j-tile 1
    {
        const short8 k0a = *(const short8*)(Kb + (size_t)(wj * 32 + ln) * DD + q * 8);
        const short8 k0b = *(const short8*)(Kb + (size_t)(wj * 32 + 16 + ln) * DD + q * 8);
        Sphase(0, k0a, k0b);
    }
    short8 kAa = *(const short8*)(Kb + (size_t)(128 + wj * 32 + ln) * DD + q * 8);
    short8 kAb = *(const short8*)(Kb + (size_t)(128 + wj * 32 + 16 + ln) * DD + q * 8);

    for (int n = 0; n < 15; ++n) {
        const int jb = n * 128 + wj * 32;
        const int jb2 = ((n <= 13) ? (n + 2) : 15) * 128 + wj * 32;

        // V loads for PV_n (consumed after S_{n+1} -> latency hidden)
        short8 vf[8];
#pragma unroll
        for (int ct = 0; ct < 8; ++ct)
            vf[ct] = *(const short8*)(Vb + (size_t)(ct * 16 + ln) * LL + jb + q * 8);
        // K prefetch for j-tile n+2
        const short8 kBa = *(const short8*)(Kb + (size_t)(jb2 + ln) * DD + q * 8);
        const short8 kBb = *(const short8*)(Kb + (size_t)(jb2 + 16 + ln) * DD + q * 8);

        // read P_n frags (wait lands before PV, overlapped by S phase)
        const u16* pr = &pbuf[n & 1][w][0];
        short8 pf[4];
#pragma unroll
        for (int it = 0; it < 4; ++it)
            pf[it] = *(const short8*)(&pr[(it * 16 + ln) * 40 + q * 8]);

        // S_{n+1} -> pbuf[(n+1)&1] (other buffer; overlaps PV_n's waits)
        Sphase((n + 1) & 1, kAa, kAb);

        // PV_n: O^T += V.P^T over exclusive 128-c half
#pragma unroll
        for (int ct = 0; ct < 8; ++ct)
#pragma unroll
            for (int it = 0; it < 4; ++it)
                oacc[ct][it] = __builtin_amdgcn_mfma_f32_16x16x32_bf16(vf[ct], pf[it], oacc[ct][it], 0, 0, 0);

        kAa = kBa; kAb = kBb;
    }

    // epilogue: PV_15 (P already in pbuf[1])
    {
        const int jb = 15 * 128 + wj * 32;
        short8 vf[8];
#pragma unroll
        for (int ct = 0; ct < 8; ++ct)
            vf[ct] = *(const short8*)(Vb + (size_t)(ct * 16 + ln) * LL + jb + q * 8);
        const u16* pr = &pbuf[1][w][0];
        short8 pf[4];
#pragma unroll
        for (int it = 0; it < 4; ++it)
            pf[it] = *(const short8*)(&pr[(it * 16 + ln) * 40 + q * 8]);
#pragma unroll
        for (int ct = 0; ct < 8; ++ct)
#pragma unroll
            for (int it = 0; it < 4; ++it)
                oacc[ct][it] = __builtin_amdgcn_mfma_f32_16x16x32_bf16(vf[ct], pf[it], oacc[ct][it], 0, 0, 0);
    }

    // ---- l: reduce over q within wave; publish per-wave partials ----
#pragma unroll
    for (int it = 0; it < 4; ++it) {
        float s = lsum[it];
        s += __shfl_xor(s, 16);
        s += __shfl_xor(s, 32);
        lsum[it] = s;
    }
    if (q == 0) {
#pragma unroll
        for (int it = 0; it < 4; ++it) lbuf[w * 64 + it * 16 + ln] = lsum[it];
    }

    // ---- O reduction over wj (4 serialized passes, disjoint c across wc) ----
#pragma unroll
    for (int p = 0; p < 4; ++p) {
        if (wj == p) {
#pragma unroll
            for (int ct = 0; ct < 8; ++ct)
#pragma unroll
                for (int it = 0; it < 4; ++it) {
                    const int i = it * 16 + ln;
#pragma unroll
                    for (int r = 0; r < 4; ++r) {
                        const int c = wc * 128 + ct * 16 + q * 4 + r;
                        if (p == 0) obuf[c * 68 + i] = oacc[ct][it][r];
                        else        obuf[c * 68 + i] += oacc[ct][it][r];
                    }
                }
        }
        __syncthreads();
    }

    // ---- finalize: out = gamma * O/l + x (coalesced float4) ----
    // lbuf summed over all 8 waves double-counts l (2 wc duplicates) -> 2/s.
    const float g = gamma[0];
    const int i4 = (tid & 15) * 4;
    float4 sv = {0.f, 0.f, 0.f, 0.f};
#pragma unroll
    for (int ww = 0; ww < 8; ++ww) {
        const float4 lv = *(const float4*)&lbuf[ww * 64 + i4];
        sv.x += lv.x; sv.y += lv.y; sv.z += lv.z; sv.w += lv.w;
    }
    float4 li;
    li.x = 2.0f * frcp(sv.x); li.y = 2.0f * frcp(sv.y);
    li.z = 2.0f * frcp(sv.z); li.w = 2.0f * frcp(sv.w);

#pragma unroll
    for (int cc = 0; cc < 8; ++cc) {
        const int c = cc * 32 + (tid >> 4);
        const float4 ov = *(const float4*)&obuf[c * 68 + i4];
        const size_t idx = ((size_t)(b * CC + c)) * LL + i0 + i4;
        const float4 xv = *(const float4*)(x + idx);
        float4 o;
        o.x = g * (ov.x * li.x) + xv.x;
        o.y = g * (ov.y * li.y) + xv.y;
        o.z = g * (ov.z * li.z) + xv.z;
        o.w = g * (ov.w * li.w) + xv.w;
        *(float4*)(out + idx) = o;
    }
}

// ---------------- launcher ----------------
extern "C" void kernel_launch(void* const* d_in, const int* in_sizes, int n_in,
                              void* d_out, int out_size, void* d_ws, size_t ws_size,
                              hipStream_t stream)
{
    const float* x     = (const float*)d_in[0];
    const float* Wq    = (const float*)d_in[1];
    const float* bq    = (const float*)d_in[2];
    const float* Wk    = (const float*)d_in[3];
    const float* bk    = (const float*)d_in[4];
    const float* Wv    = (const float*)d_in[5];
    const float* bv    = (const float*)d_in[6];
    const float* gamma = (const float*)d_in[7];
    float* out = (float*)d_out;

    uint8_t* ws = (uint8_t*)d_ws;
    u16* Wh  = (u16*)(ws + 0x000000);
    u16* Qh  = (u16*)(ws + 0x040000);
    u16* Kth = (u16*)(ws + 0x140000);
    u16* Vh  = (u16*)(ws + 0x240000);

    prep_w_kernel<<<80, 256, 0, stream>>>(Wq, Wk, Wv, Wh);
    proj_kernel<<<512, 512, 0, stream>>>(x, Wh, bq, bk, bv, Qh, Kth, Vh);
    attn_kernel<<<256, 512, 0, stream>>>(Qh, Kth, Vh, x, gamma, out);
}